// Round 4
// baseline (285.262 us; speedup 1.0000x reference)
//
#include <hip/hip_runtime.h>
#include <hip/hip_bf16.h>
#include <stdint.h>

typedef unsigned short u16;
typedef short bf16x8 __attribute__((ext_vector_type(8)));
typedef float f32x4 __attribute__((ext_vector_type(4)));

#define DEVI static __device__ __forceinline__

#if __has_builtin(__builtin_amdgcn_exp2f)
#define EXP2F(x) __builtin_amdgcn_exp2f(x)
#else
#define EXP2F(x) exp2f(x)
#endif

DEVI u16 f2bf(float f) {
  union { float f; uint32_t u; } v; v.f = f;
  uint32_t u = v.u;
  u += 0x7fffu + ((u >> 16) & 1u);   // round-to-nearest-even
  return (u16)(u >> 16);
}
DEVI uint32_t pk2bf(float lo, float hi) {
  __hip_bfloat162 h = __float22bfloat162_rn(float2{lo, hi});
  union { __hip_bfloat162 h; uint32_t u; } v; v.h = h; return v.u;
}

DEVI void async16(const void* g, const void* l) {
  __builtin_amdgcn_global_load_lds(
      (const __attribute__((address_space(1))) void*)g,
      (__attribute__((address_space(3))) void*)l, 16, 0, 0);
}

DEVI f32x4 mfma16(bf16x8 a, bf16x8 b, f32x4 c) {
  return __builtin_amdgcn_mfma_f32_16x16x32_bf16(a, b, c, 0, 0, 0);
}

// ---------------------------------------------------------------- constants
// B=2, S=2048, H=1024, NH=16, D=64, M=B*S=4096
// log2(e)/sqrt(64): folded into Q at the qkv epilogue
#define CSC 0.18033688011112042f

// ------------------------------------------------- kernel 1: fp32 -> bf16 x
__global__ void convx(const float* __restrict__ q, const float* __restrict__ k,
                      const float* __restrict__ v, u16* __restrict__ out) {
  const int z = blockIdx.y;
  const float* src = (z == 0) ? q : (z == 1) ? k : v;
  const int i = (blockIdx.x * 256 + threadIdx.x) * 4;
  float4 f = *(const float4*)(src + i);
  ushort4 o;
  o.x = f2bf(f.x); o.y = f2bf(f.y); o.z = f2bf(f.z); o.w = f2bf(f.w);
  *(ushort4*)(out + (size_t)z * 4194304 + i) = o;
}

// ----------------------------------- kernel 2: W[k][n] -> Wt[n][k] in bf16
__global__ void transw(const float* __restrict__ Wq, const float* __restrict__ Wk,
                       const float* __restrict__ Wv, const float* __restrict__ Wo,
                       u16* __restrict__ WT) {
  __shared__ u16 tile[64 * 68];
  const int z = blockIdx.z;
  const float* W = (z == 0) ? Wq : (z == 1) ? Wk : (z == 2) ? Wv : Wo;
  u16* out = WT + (size_t)z * 1048576;
  const int R0 = blockIdx.y * 64, C0 = blockIdx.x * 64;
  const int t = threadIdx.x;
#pragma unroll
  for (int it = 0; it < 16; ++it) {
    int j = it * 256 + t;
    int r = j >> 6, c = j & 63;
    tile[r * 68 + c] = f2bf(W[(size_t)(R0 + r) * 1024 + C0 + c]);
  }
  __syncthreads();
#pragma unroll
  for (int it = 0; it < 16; ++it) {
    int j = it * 256 + t;
    int c = j >> 6, r = j & 63;
    out[(size_t)(C0 + c) * 1024 + R0 + r] = tile[r * 68 + c];
  }
}

// -------------------------------------------------- fused QKV projection GEMM
// BK=64, 16 k-iters. z=0:Q (pre-scaled by CSC) z=1:K -> [b,h,s,d]; z=2:V -> [b,h,d,s]
// z<2 computes C^T (operand-swapped mfma) so the register dim is n(=d):
// epilogue packs reg-quads into ushort4 stores (16 stores vs 64 scalar).
__global__ __launch_bounds__(256, 3)
void qkv_gemm(const u16* __restrict__ XB, const u16* __restrict__ WT,
              const float* __restrict__ bq, const float* __restrict__ bk,
              const float* __restrict__ bv,
              u16* __restrict__ QH, u16* __restrict__ KH, u16* __restrict__ VT) {
  __shared__ u16 lA[128 * 64];
  __shared__ u16 lB[128 * 64];
  const int z = blockIdx.z;
  const u16* A  = XB + (size_t)z * 4194304;
  const u16* Bt = WT + (size_t)z * 1048576;
  const float* bias = (z == 0) ? bq : (z == 1) ? bk : bv;
  const int t = threadIdx.x, lane = t & 63, w = t >> 6;
  const int quad = lane >> 4, l16 = lane & 15;
  const int wm = (w & 1) * 64, wn = (w >> 1) * 64;
  const int n0 = blockIdx.x * 128, m0 = blockIdx.y * 128;

  f32x4 acc[4][4] = {};
  for (int kt = 0; kt < 16; ++kt) {
    const int k0 = kt * 64;
#pragma unroll
    for (int it = 0; it < 4; ++it) {
      int i = it * 256 + t;
      int r = i >> 3, cc = i & 7, c = cc ^ (r & 7);
      async16(A + (size_t)(m0 + r) * 1024 + k0 + c * 8, &lA[i * 8]);
      async16(Bt + (size_t)(n0 + r) * 1024 + k0 + c * 8, &lB[i * 8]);
    }
    __syncthreads();
#pragma unroll
    for (int ks = 0; ks < 2; ++ks) {
      bf16x8 af[4], bfr[4];
#pragma unroll
      for (int rt = 0; rt < 4; ++rt) {
        int row = wm + rt * 16 + l16;
        af[rt] = *(const bf16x8*)&lA[row * 64 + ((ks * 4 + quad) ^ (row & 7)) * 8];
      }
#pragma unroll
      for (int ct = 0; ct < 4; ++ct) {
        int row = wn + ct * 16 + l16;
        bfr[ct] = *(const bf16x8*)&lB[row * 64 + ((ks * 4 + quad) ^ (row & 7)) * 8];
      }
      if (z < 2) {
#pragma unroll
        for (int rt = 0; rt < 4; ++rt)
#pragma unroll
          for (int ct = 0; ct < 4; ++ct)
            acc[rt][ct] = mfma16(bfr[ct], af[rt], acc[rt][ct]);  // C^T
      } else {
#pragma unroll
        for (int rt = 0; rt < 4; ++rt)
#pragma unroll
          for (int ct = 0; ct < 4; ++ct)
            acc[rt][ct] = mfma16(af[rt], bfr[ct], acc[rt][ct]);
      }
    }
    __syncthreads();
  }

  if (z < 2) {
    // C^T: col(lane&15) = m-row, regs = n (d contiguous in reg quad)
    u16* out = (z == 0) ? QH : KH;
    const float scl = (z == 0) ? CSC : 1.0f;
#pragma unroll
    for (int rt = 0; rt < 4; ++rt) {
      int mm = m0 + wm + rt * 16 + l16;
      int bb = mm >> 11, s = mm & 2047;
#pragma unroll
      for (int ct = 0; ct < 4; ++ct) {
        int nb = n0 + wn + ct * 16 + quad * 4;
        int hh = nb >> 6, d = nb & 63;
        float4 b4 = *(const float4*)&bias[nb];
        ushort4 pk;
        pk.x = f2bf((acc[rt][ct][0] + b4.x) * scl);
        pk.y = f2bf((acc[rt][ct][1] + b4.y) * scl);
        pk.z = f2bf((acc[rt][ct][2] + b4.z) * scl);
        pk.w = f2bf((acc[rt][ct][3] + b4.w) * scl);
        *(ushort4*)&out[((size_t)((bb * 16 + hh) * 2048 + s)) * 64 + d] = pk;
      }
    }
  } else {
    // C: col = n (d), regs = m (s contiguous) -> VT[b,h,d,s]
#pragma unroll
    for (int rt = 0; rt < 4; ++rt) {
      int mb = m0 + wm + rt * 16 + quad * 4;
      int bb = mb >> 11, sb = mb & 2047;
#pragma unroll
      for (int ct = 0; ct < 4; ++ct) {
        int ncol = n0 + wn + ct * 16 + l16;
        int hh = ncol >> 6, d = ncol & 63;
        float bvv = bias[ncol];
        ushort4 pk;
        pk.x = f2bf(acc[rt][ct][0] + bvv);
        pk.y = f2bf(acc[rt][ct][1] + bvv);
        pk.z = f2bf(acc[rt][ct][2] + bvv);
        pk.w = f2bf(acc[rt][ct][3] + bvv);
        *(ushort4*)&VT[((size_t)((bb * 16 + hh) * 64 + d)) * 2048 + sb] = pk;
      }
    }
  }
}

// -------------------------------------------------------- flash attention v4
// 256 threads (4 waves x 32 q rows). S^T formulation, no running max,
// Sk-tile=64, double-buffered K/V, one barrier/tile, per-wave padded lPT.
// K/V-frag LDS reads amortized over 2 q-subtiles per wave. grid (16,16,2).
__global__ __launch_bounds__(256, 2)
void attn4(const u16* __restrict__ QH, const u16* __restrict__ KH,
           const u16* __restrict__ VT, u16* __restrict__ AO) {
  __shared__ u16 lK[2][64 * 64];
  __shared__ u16 lV[2][64 * 64];
  __shared__ u16 lPT[4][32 * 72];   // stride 72: 2-way max on writes/reads
  const int qt0 = blockIdx.x, h = blockIdx.y, b = blockIdx.z;
  const int t = threadIdx.x, lane = t & 63, w = t >> 6;
  const int quad = lane >> 4, l16 = lane & 15;
  const u16* Qg = QH + ((size_t)((b * 16 + h) * 2048 + qt0 * 128)) * 64;
  const u16* Kg = KH + ((size_t)((b * 16 + h) * 2048)) * 64;
  const u16* Vg = VT + ((size_t)((b * 16 + h) * 64)) * 2048;

  // Q fragments straight from global (pre-scaled by CSC in qkv_gemm)
  bf16x8 qf[2][2];
#pragma unroll
  for (int qt = 0; qt < 2; ++qt)
#pragma unroll
    for (int ks = 0; ks < 2; ++ks)
      qf[qt][ks] = *(const bf16x8*)(Qg + (size_t)(w * 32 + qt * 16 + l16) * 64 +
                                    ks * 32 + quad * 8);

  // stage tile 0: K [64 sk][64 d], V [64 d][64 sk]
#pragma unroll
  for (int it = 0; it < 2; ++it) {
    int s = it * 256 + t;
    int r = s >> 3, cc = s & 7, c = cc ^ (r & 7);
    async16(Kg + (size_t)r * 64 + c * 8, &lK[0][s * 8]);
    async16(Vg + (size_t)r * 2048 + c * 8, &lV[0][s * 8]);
  }
  __syncthreads();

  f32x4 o[2][4] = {};
  float lsum[2] = {0.f, 0.f};
  u16* myP = &lPT[w][0];

  for (int kt = 0; kt < 32; ++kt) {
    const int cur = kt & 1, nxt = cur ^ 1;
    if (kt + 1 < 32) {
      const int kb = (kt + 1) * 64;
#pragma unroll
      for (int it = 0; it < 2; ++it) {
        int s = it * 256 + t;
        int r = s >> 3, cc = s & 7, c = cc ^ (r & 7);
        async16(Kg + (size_t)(kb + r) * 64 + c * 8, &lK[nxt][s * 8]);
        async16(Vg + (size_t)r * 2048 + kb + c * 8, &lV[nxt][s * 8]);
      }
    }

    // ---- QK^T -> S^T: rows sk (st*16+quad*4+r), cols q (l16); kf shared by 2 qt
    f32x4 sc[2][4];
#pragma unroll
    for (int st = 0; st < 4; ++st) {
      int row = st * 16 + l16;
      bf16x8 kf0 = *(const bf16x8*)&lK[cur][row * 64 + ((quad) ^ (row & 7)) * 8];
      bf16x8 kf1 = *(const bf16x8*)&lK[cur][row * 64 + ((4 + quad) ^ (row & 7)) * 8];
      f32x4 z = {};
      sc[0][st] = mfma16(kf0, qf[0][0], z);
      sc[0][st] = mfma16(kf1, qf[0][1], sc[0][st]);
      sc[1][st] = mfma16(kf0, qf[1][0], z);
      sc[1][st] = mfma16(kf1, qf[1][1], sc[1][st]);
    }

    // ---- p = exp2(s); pack RNE bf16 pairs; l += fp32 p
#pragma unroll
    for (int qt = 0; qt < 2; ++qt) {
      int prow = qt * 16 + l16;
#pragma unroll
      for (int st = 0; st < 4; ++st) {
        float p0 = EXP2F(sc[qt][st][0]);
        float p1 = EXP2F(sc[qt][st][1]);
        float p2 = EXP2F(sc[qt][st][2]);
        float p3 = EXP2F(sc[qt][st][3]);
        lsum[qt] += (p0 + p1) + (p2 + p3);
        uint2 pk;
        pk.x = pk2bf(p0, p1);
        pk.y = pk2bf(p2, p3);
        *(uint2*)&myP[prow * 72 + st * 16 + quad * 4] = pk;
      }
    }

    // ---- PV: O^T += V^T(64d x 64sk) * P(32q x 64sk); vf shared by 2 qt
#pragma unroll
    for (int ks2 = 0; ks2 < 2; ++ks2) {
      bf16x8 pf0 = *(const bf16x8*)&myP[(l16) * 72 + ks2 * 32 + quad * 8];
      bf16x8 pf1 = *(const bf16x8*)&myP[(16 + l16) * 72 + ks2 * 32 + quad * 8];
#pragma unroll
      for (int dt = 0; dt < 4; ++dt) {
        int row = dt * 16 + l16;
        bf16x8 vf = *(const bf16x8*)&lV[cur][row * 64 + ((ks2 * 4 + quad) ^ (row & 7)) * 8];
        o[0][dt] = mfma16(vf, pf0, o[0][dt]);
        o[1][dt] = mfma16(vf, pf1, o[1][dt]);
      }
    }
    __syncthreads();
  }

  // ---- epilogue: O^T/l -> AO [b][s][h*64+d] bf16 (4 consecutive d per lane)
#pragma unroll
  for (int qt = 0; qt < 2; ++qt) {
    float l = lsum[qt];
    l += __shfl_xor(l, 16, 64);
    l += __shfl_xor(l, 32, 64);
    float inv = 1.0f / l;
    int qglob = qt0 * 128 + w * 32 + qt * 16 + l16;
    size_t base = ((size_t)(b * 2048 + qglob)) * 1024 + h * 64;
#pragma unroll
    for (int dt = 0; dt < 4; ++dt) {
      ushort4 pk;
      pk.x = f2bf(o[qt][dt][0] * inv);
      pk.y = f2bf(o[qt][dt][1] * inv);
      pk.z = f2bf(o[qt][dt][2] * inv);
      pk.w = f2bf(o[qt][dt][3] * inv);
      *(ushort4*)&AO[base + dt * 16 + quad * 4] = pk;
    }
  }
}

// ------------------------------------------------------- output projection
// 128m x 64n tiles, BK=64 -> 512 blocks. C^T orientation: regs = n -> float4 stores.
__global__ __launch_bounds__(256, 2)
void oproj_gemm(const u16* __restrict__ AO, const u16* __restrict__ Bt,
                const float* __restrict__ bias, float* __restrict__ out) {
  __shared__ u16 lA[128 * 64];
  __shared__ u16 lB[64 * 64];
  const int t = threadIdx.x, lane = t & 63, w = t >> 6;
  const int quad = lane >> 4, l16 = lane & 15;
  const int wm = (w & 1) * 64, wn = (w >> 1) * 32;
  const int n0 = blockIdx.x * 64, m0 = blockIdx.y * 128;

  f32x4 acc[4][2] = {};
  for (int kt = 0; kt < 16; ++kt) {
    const int k0 = kt * 64;
#pragma unroll
    for (int it = 0; it < 4; ++it) {
      int i = it * 256 + t;
      int r = i >> 3, cc = i & 7, c = cc ^ (r & 7);
      async16(AO + (size_t)(m0 + r) * 1024 + k0 + c * 8, &lA[i * 8]);
    }
#pragma unroll
    for (int it = 0; it < 2; ++it) {
      int i = it * 256 + t;
      int r = i >> 3, cc = i & 7, c = cc ^ (r & 7);
      async16(Bt + (size_t)(n0 + r) * 1024 + k0 + c * 8, &lB[i * 8]);
    }
    __syncthreads();
#pragma unroll
    for (int ks = 0; ks < 2; ++ks) {
      bf16x8 af[4], bfr[2];
#pragma unroll
      for (int rt = 0; rt < 4; ++rt) {
        int row = wm + rt * 16 + l16;
        af[rt] = *(const bf16x8*)&lA[row * 64 + ((ks * 4 + quad) ^ (row & 7)) * 8];
      }
#pragma unroll
      for (int ct = 0; ct < 2; ++ct) {
        int row = wn + ct * 16 + l16;
        bfr[ct] = *(const bf16x8*)&lB[row * 64 + ((ks * 4 + quad) ^ (row & 7)) * 8];
      }
#pragma unroll
      for (int rt = 0; rt < 4; ++rt)
#pragma unroll
        for (int ct = 0; ct < 2; ++ct)
          acc[rt][ct] = mfma16(bfr[ct], af[rt], acc[rt][ct]);  // C^T
    }
    __syncthreads();
  }

#pragma unroll
  for (int rt = 0; rt < 4; ++rt) {
    int m = m0 + wm + rt * 16 + l16;
#pragma unroll
    for (int ct = 0; ct < 2; ++ct) {
      int nb = n0 + wn + ct * 16 + quad * 4;
      float4 b4 = *(const float4*)&bias[nb];
      float4 st;
      st.x = acc[rt][ct][0] + b4.x;
      st.y = acc[rt][ct][1] + b4.y;
      st.z = acc[rt][ct][2] + b4.z;
      st.w = acc[rt][ct][3] + b4.w;
      *(float4*)&out[(size_t)m * 1024 + nb] = st;
    }
  }
}

// ------------------------------------------------------------------ launch
extern "C" void kernel_launch(void* const* d_in, const int* in_sizes, int n_in,
                              void* d_out, int out_size, void* d_ws, size_t ws_size,
                              hipStream_t stream) {
  const float* query = (const float*)d_in[0];
  const float* key   = (const float*)d_in[1];
  const float* value = (const float*)d_in[2];
  const float* Wq = (const float*)d_in[3];
  const float* bq = (const float*)d_in[4];
  const float* Wk = (const float*)d_in[5];
  const float* bk = (const float*)d_in[6];
  const float* Wv = (const float*)d_in[7];
  const float* bv = (const float*)d_in[8];
  const float* Wo = (const float*)d_in[9];
  const float* bo = (const float*)d_in[10];
  float* out = (float*)d_out;

  // workspace layout (u16 elements): total 28M u16 = 56 MB
  u16* WT = (u16*)d_ws;              // 4 x 1M  (Wq_t, Wk_t, Wv_t, Wo_t)
  u16* QH = WT + 4 * 1048576;        // 4M  [b,h,s,d]  (Q pre-scaled by CSC)
  u16* KH = QH + 4194304;            // 4M  [b,h,s,d]
  u16* VT = KH + 4194304;            // 4M  [b,h,d,s]
  u16* XB = VT + 4194304;            // 3 x 4M bf16 copies of q,k,v
  u16* AO = XB;                      // attn out aliases XB (dead by then)

  convx<<<dim3(4096, 3), 256, 0, stream>>>(query, key, value, XB);
  transw<<<dim3(16, 16, 4), 256, 0, stream>>>(Wq, Wk, Wv, Wo, WT);
  qkv_gemm<<<dim3(8, 32, 3), 256, 0, stream>>>(XB, WT, bq, bk, bv, QH, KH, VT);
  attn4<<<dim3(16, 16, 2), 256, 0, stream>>>(QH, KH, VT, AO);
  oproj_gemm<<<dim3(16, 32), 256, 0, stream>>>(AO, WT + 3 * 1048576, bo, out);
}

// Round 5
// 218.674 us; speedup vs baseline: 1.3045x; 1.3045x over previous
//
#include <hip/hip_runtime.h>
#include <hip/hip_bf16.h>
#include <stdint.h>

typedef unsigned short u16;
typedef short bf16x8 __attribute__((ext_vector_type(8)));
typedef float f32x4 __attribute__((ext_vector_type(4)));

#define DEVI static __device__ __forceinline__

#if __has_builtin(__builtin_amdgcn_exp2f)
#define EXP2F(x) __builtin_amdgcn_exp2f(x)
#else
#define EXP2F(x) exp2f(x)
#endif

DEVI u16 f2bf(float f) {
  union { float f; uint32_t u; } v; v.f = f;
  uint32_t u = v.u;
  u += 0x7fffu + ((u >> 16) & 1u);   // round-to-nearest-even
  return (u16)(u >> 16);
}
DEVI uint32_t pk2bf(float lo, float hi) {
  __hip_bfloat162 h = __float22bfloat162_rn(float2{lo, hi});
  union { __hip_bfloat162 h; uint32_t u; } v; v.h = h; return v.u;
}

DEVI void async16(const void* g, const void* l) {
  __builtin_amdgcn_global_load_lds(
      (const __attribute__((address_space(1))) void*)g,
      (__attribute__((address_space(3))) void*)l, 16, 0, 0);
}

DEVI f32x4 mfma16(bf16x8 a, bf16x8 b, f32x4 c) {
  return __builtin_amdgcn_mfma_f32_16x16x32_bf16(a, b, c, 0, 0, 0);
}

// ---------------------------------------------------------------- constants
// B=2, S=2048, H=1024, NH=16, D=64, M=B*S=4096
// log2(e)/sqrt(64): folded into Q at the qkv epilogue
#define CSC 0.18033688011112042f

// ------------------------------------------------- kernel 1: fp32 -> bf16 x
__global__ void convx(const float* __restrict__ q, const float* __restrict__ k,
                      const float* __restrict__ v, u16* __restrict__ out) {
  const int z = blockIdx.y;
  const float* src = (z == 0) ? q : (z == 1) ? k : v;
  const int i = (blockIdx.x * 256 + threadIdx.x) * 4;
  float4 f = *(const float4*)(src + i);
  ushort4 o;
  o.x = f2bf(f.x); o.y = f2bf(f.y); o.z = f2bf(f.z); o.w = f2bf(f.w);
  *(ushort4*)(out + (size_t)z * 4194304 + i) = o;
}

// ----------------------------------- kernel 2: W[k][n] -> Wt[n][k] in bf16
__global__ void transw(const float* __restrict__ Wq, const float* __restrict__ Wk,
                       const float* __restrict__ Wv, const float* __restrict__ Wo,
                       u16* __restrict__ WT) {
  __shared__ u16 tile[64 * 68];
  const int z = blockIdx.z;
  const float* W = (z == 0) ? Wq : (z == 1) ? Wk : (z == 2) ? Wv : Wo;
  u16* out = WT + (size_t)z * 1048576;
  const int R0 = blockIdx.y * 64, C0 = blockIdx.x * 64;
  const int t = threadIdx.x;
#pragma unroll
  for (int it = 0; it < 16; ++it) {
    int j = it * 256 + t;
    int r = j >> 6, c = j & 63;
    tile[r * 68 + c] = f2bf(W[(size_t)(R0 + r) * 1024 + C0 + c]);
  }
  __syncthreads();
#pragma unroll
  for (int it = 0; it < 16; ++it) {
    int j = it * 256 + t;
    int c = j >> 6, r = j & 63;
    out[(size_t)(C0 + c) * 1024 + R0 + r] = tile[r * 68 + c];
  }
}

// -------------------------------------------------- fused QKV projection GEMM
// BK=64, 16 k-iters, uniform C^T orientation (regs = n = d-dim) for ALL z.
// Epilogue bounces acc through LDS so every global store is a 256B-contiguous
// run (full-line coverage). z=0: Q natural [b,s,1024] pre-scaled by CSC;
// z=1: K natural [b,s,1024]; z=2: V^T [b,h,d,s].
// XCD swizzle: 1-D grid of 256 tiles, m_tile = T&31 -> same-A-stripe blocks
// share an XCD (xcd = T%8 = m%8); per-XCD: 4 A-stripes + full B = 3MB < 4MB L2.
__global__ __launch_bounds__(256, 3)
void qkv_gemm(const u16* __restrict__ XB, const u16* __restrict__ WT,
              const float* __restrict__ bq, const float* __restrict__ bk,
              const float* __restrict__ bv,
              u16* __restrict__ QN, u16* __restrict__ KN, u16* __restrict__ VT) {
  __shared__ u16 smem[16896];          // lA(8192) + lB(8192); reused as 128x132 bounce
  u16* lA = smem;
  u16* lB = smem + 8192;
  const int z = blockIdx.y;
  const u16* A  = XB + (size_t)z * 4194304;
  const u16* Bt = WT + (size_t)z * 1048576;
  const float* bias = (z == 0) ? bq : (z == 1) ? bk : bv;
  const int T = blockIdx.x;
  const int m0 = (T & 31) * 128, n0 = (T >> 5) * 128;
  const int t = threadIdx.x, lane = t & 63, w = t >> 6;
  const int quad = lane >> 4, l16 = lane & 15;
  const int wm = (w & 1) * 64, wn = (w >> 1) * 64;

  f32x4 acc[4][4] = {};
  for (int kt = 0; kt < 16; ++kt) {
    const int k0 = kt * 64;
#pragma unroll
    for (int it = 0; it < 4; ++it) {
      int i = it * 256 + t;
      int r = i >> 3, cc = i & 7, c = cc ^ (r & 7);
      async16(A + (size_t)(m0 + r) * 1024 + k0 + c * 8, &lA[i * 8]);
      async16(Bt + (size_t)(n0 + r) * 1024 + k0 + c * 8, &lB[i * 8]);
    }
    __syncthreads();
#pragma unroll
    for (int ks = 0; ks < 2; ++ks) {
      bf16x8 af[4], bfr[4];
#pragma unroll
      for (int rt = 0; rt < 4; ++rt) {
        int row = wm + rt * 16 + l16;
        af[rt] = *(const bf16x8*)&lA[row * 64 + ((ks * 4 + quad) ^ (row & 7)) * 8];
      }
#pragma unroll
      for (int ct = 0; ct < 4; ++ct) {
        int row = wn + ct * 16 + l16;
        bfr[ct] = *(const bf16x8*)&lB[row * 64 + ((ks * 4 + quad) ^ (row & 7)) * 8];
      }
#pragma unroll
      for (int rt = 0; rt < 4; ++rt)
#pragma unroll
        for (int ct = 0; ct < 4; ++ct)
          acc[rt][ct] = mfma16(bfr[ct], af[rt], acc[rt][ct]);  // C^T: regs = d
    }
    __syncthreads();
  }

  // ---- epilogue via LDS bounce (all waves past final barrier; smem reusable)
  if (z < 2) {
    const float scl = (z == 0) ? CSC : 1.0f;
    // acc -> smem[s][132 + d]  (s-local = wm+rt*16+l16, d-local = wn+ct*16+quad*4)
#pragma unroll
    for (int rt = 0; rt < 4; ++rt) {
      int sl = wm + rt * 16 + l16;
#pragma unroll
      for (int ct = 0; ct < 4; ++ct) {
        int nb = wn + ct * 16 + quad * 4;
        float4 b4 = *(const float4*)&bias[n0 + nb];
        ushort4 pk;
        pk.x = f2bf((acc[rt][ct][0] + b4.x) * scl);
        pk.y = f2bf((acc[rt][ct][1] + b4.y) * scl);
        pk.z = f2bf((acc[rt][ct][2] + b4.z) * scl);
        pk.w = f2bf((acc[rt][ct][3] + b4.w) * scl);
        *(ushort4*)&smem[sl * 132 + nb] = pk;
      }
    }
    __syncthreads();
    // coalesced store: natural [4096][1024]; 256B-contiguous per 16 lanes
    u16* out = (z == 0) ? QN : KN;
#pragma unroll
    for (int p = 0; p < 8; ++p) {
      int idx = p * 256 + t;
      int row = idx >> 4, chunk = idx & 15;
      *(bf16x8*)&out[(size_t)(m0 + row) * 1024 + n0 + chunk * 8] =
          *(const bf16x8*)&smem[row * 132 + chunk * 8];
    }
  } else {
    // acc -> smem[d][132 + s] (transpose via scalar LDS writes)
#pragma unroll
    for (int rt = 0; rt < 4; ++rt) {
      int sl = wm + rt * 16 + l16;
#pragma unroll
      for (int ct = 0; ct < 4; ++ct) {
        int nb = wn + ct * 16 + quad * 4;
        float4 b4 = *(const float4*)&bias[n0 + nb];
        smem[(nb + 0) * 132 + sl] = f2bf(acc[rt][ct][0] + b4.x);
        smem[(nb + 1) * 132 + sl] = f2bf(acc[rt][ct][1] + b4.y);
        smem[(nb + 2) * 132 + sl] = f2bf(acc[rt][ct][2] + b4.z);
        smem[(nb + 3) * 132 + sl] = f2bf(acc[rt][ct][3] + b4.w);
      }
    }
    __syncthreads();
    // coalesced store: VT[b,h,d,s]; 256B-contiguous per 16 lanes
    const int bb = m0 >> 11, sb = m0 & 2047;
#pragma unroll
    for (int p = 0; p < 8; ++p) {
      int idx = p * 256 + t;
      int dl = idx >> 4, chunk = idx & 15;
      int ncol = n0 + dl, hh = ncol >> 6, dd = ncol & 63;
      *(bf16x8*)&VT[((size_t)((bb * 16 + hh) * 64 + dd)) * 2048 + sb + chunk * 8] =
          *(const bf16x8*)&smem[dl * 132 + chunk * 8];
    }
  }
}

// -------------------------------------------------------- flash attention
// attn3 structure (R3: 57.7us): 512 threads (8 waves x 16 q rows), S^T
// formulation, no running max, Sk-tile=64, double-buffered K/V, one
// barrier/tile. Q/K now natural [b,s,1024] layout. grid (16,16,2).
__global__ __launch_bounds__(512, 4)
void attn5(const u16* __restrict__ QN, const u16* __restrict__ KN,
           const u16* __restrict__ VT, u16* __restrict__ AO) {
  __shared__ u16 lK[2][64 * 64];
  __shared__ u16 lV[2][64 * 64];
  __shared__ u16 lPT[8][16 * 72];
  const int qt0 = blockIdx.x, h = blockIdx.y, b = blockIdx.z;
  const int t = threadIdx.x, lane = t & 63, w = t >> 6;
  const int quad = lane >> 4, l16 = lane & 15;
  const u16* Qg = QN + ((size_t)(b * 2048 + qt0 * 128)) * 1024 + h * 64;
  const u16* Kg = KN + ((size_t)b * 2048) * 1024 + h * 64;
  const u16* Vg = VT + ((size_t)((b * 16 + h) * 64)) * 2048;

  // Q fragments straight from global (pre-scaled by CSC in qkv_gemm)
  bf16x8 qf[2];
#pragma unroll
  for (int ks = 0; ks < 2; ++ks)
    qf[ks] = *(const bf16x8*)(Qg + (size_t)(w * 16 + l16) * 1024 + ks * 32 + quad * 8);

  // stage tile 0: K rows (natural, stride 1024), V rows (VT, stride 2048)
  {
    int r = t >> 3, cc = t & 7, c = cc ^ (r & 7);
    async16(Kg + (size_t)r * 1024 + c * 8, &lK[0][t * 8]);
    async16(Vg + (size_t)r * 2048 + c * 8, &lV[0][t * 8]);
  }
  __syncthreads();

  f32x4 o[4] = {};
  float lsum = 0.f;
  u16* myP = &lPT[w][0];

  for (int kt = 0; kt < 32; ++kt) {
    const int cur = kt & 1, nxt = cur ^ 1;
    if (kt + 1 < 32) {
      const int kb = (kt + 1) * 64;
      int r = t >> 3, cc = t & 7, c = cc ^ (r & 7);
      async16(Kg + (size_t)(kb + r) * 1024 + c * 8, &lK[nxt][t * 8]);
      async16(Vg + (size_t)r * 2048 + kb + c * 8, &lV[nxt][t * 8]);
    }

    // ---- QK^T -> S^T: rows sk (st*16+quad*4+r), cols q (l16)
    f32x4 sc[4];
#pragma unroll
    for (int st = 0; st < 4; ++st) {
      int row = st * 16 + l16;
      bf16x8 kf0 = *(const bf16x8*)&lK[cur][row * 64 + ((quad) ^ (row & 7)) * 8];
      bf16x8 kf1 = *(const bf16x8*)&lK[cur][row * 64 + ((4 + quad) ^ (row & 7)) * 8];
      f32x4 z = {};
      sc[st] = mfma16(kf0, qf[0], z);
      sc[st] = mfma16(kf1, qf[1], sc[st]);
    }

    // ---- p = exp2(s); pack RNE bf16 pairs; l += fp32 p
#pragma unroll
    for (int st = 0; st < 4; ++st) {
      float p0 = EXP2F(sc[st][0]);
      float p1 = EXP2F(sc[st][1]);
      float p2 = EXP2F(sc[st][2]);
      float p3 = EXP2F(sc[st][3]);
      lsum += (p0 + p1) + (p2 + p3);
      uint2 pk;
      pk.x = pk2bf(p0, p1);
      pk.y = pk2bf(p2, p3);
      *(uint2*)&myP[l16 * 72 + st * 16 + quad * 4] = pk;
    }

    // ---- PV: O^T += V^T(64d x 64sk) * P(16q x 64sk)
#pragma unroll
    for (int ks2 = 0; ks2 < 2; ++ks2) {
      bf16x8 pf = *(const bf16x8*)&myP[l16 * 72 + ks2 * 32 + quad * 8];
#pragma unroll
      for (int dt = 0; dt < 4; ++dt) {
        int row = dt * 16 + l16;
        bf16x8 vf = *(const bf16x8*)&lV[cur][row * 64 + ((ks2 * 4 + quad) ^ (row & 7)) * 8];
        o[dt] = mfma16(vf, pf, o[dt]);
      }
    }
    __syncthreads();
  }

  // ---- epilogue: O^T/l -> AO [b][s][h*64+d] bf16 (4 consecutive d per lane)
  float l = lsum;
  l += __shfl_xor(l, 16, 64);
  l += __shfl_xor(l, 32, 64);
  float inv = 1.0f / l;
  int qglob = qt0 * 128 + w * 16 + l16;
  size_t base = ((size_t)(b * 2048 + qglob)) * 1024 + h * 64;
#pragma unroll
  for (int dt = 0; dt < 4; ++dt) {
    ushort4 pk;
    pk.x = f2bf(o[dt][0] * inv);
    pk.y = f2bf(o[dt][1] * inv);
    pk.z = f2bf(o[dt][2] * inv);
    pk.w = f2bf(o[dt][3] * inv);
    *(ushort4*)&AO[base + dt * 16 + quad * 4] = pk;
  }
}

// ------------------------------------------------------- output projection
// 128m x 64n tiles, BK=64, 512 blocks, XCD swizzle (m_tile = T&31).
// Normal orientation; scalar f32 stores = 64B runs (R3-style, known-good).
__global__ __launch_bounds__(256, 2)
void oproj_gemm(const u16* __restrict__ AO, const u16* __restrict__ Bt,
                const float* __restrict__ bias, float* __restrict__ out) {
  __shared__ u16 lA[128 * 64];
  __shared__ u16 lB[64 * 64];
  const int T = blockIdx.x;
  const int m0 = (T & 31) * 128, n0 = (T >> 5) * 64;
  const int t = threadIdx.x, lane = t & 63, w = t >> 6;
  const int quad = lane >> 4, l16 = lane & 15;
  const int wm = (w & 1) * 64, wn = (w >> 1) * 32;

  f32x4 acc[4][2] = {};
  for (int kt = 0; kt < 16; ++kt) {
    const int k0 = kt * 64;
#pragma unroll
    for (int it = 0; it < 4; ++it) {
      int i = it * 256 + t;
      int r = i >> 3, cc = i & 7, c = cc ^ (r & 7);
      async16(AO + (size_t)(m0 + r) * 1024 + k0 + c * 8, &lA[i * 8]);
    }
#pragma unroll
    for (int it = 0; it < 2; ++it) {
      int i = it * 256 + t;
      int r = i >> 3, cc = i & 7, c = cc ^ (r & 7);
      async16(Bt + (size_t)(n0 + r) * 1024 + k0 + c * 8, &lB[i * 8]);
    }
    __syncthreads();
#pragma unroll
    for (int ks = 0; ks < 2; ++ks) {
      bf16x8 af[4], bfr[2];
#pragma unroll
      for (int rt = 0; rt < 4; ++rt) {
        int row = wm + rt * 16 + l16;
        af[rt] = *(const bf16x8*)&lA[row * 64 + ((ks * 4 + quad) ^ (row & 7)) * 8];
      }
#pragma unroll
      for (int ct = 0; ct < 2; ++ct) {
        int row = wn + ct * 16 + l16;
        bfr[ct] = *(const bf16x8*)&lB[row * 64 + ((ks * 4 + quad) ^ (row & 7)) * 8];
      }
#pragma unroll
      for (int rt = 0; rt < 4; ++rt)
#pragma unroll
        for (int ct = 0; ct < 2; ++ct)
          acc[rt][ct] = mfma16(af[rt], bfr[ct], acc[rt][ct]);
    }
    __syncthreads();
  }

#pragma unroll
  for (int ct = 0; ct < 2; ++ct) {
    int ncol = n0 + wn + ct * 16 + l16;
    float bvv = bias[ncol];
#pragma unroll
    for (int rt = 0; rt < 4; ++rt)
#pragma unroll
      for (int r = 0; r < 4; ++r) {
        int m = m0 + wm + rt * 16 + quad * 4 + r;
        out[(size_t)m * 1024 + ncol] = acc[rt][ct][r] + bvv;
      }
  }
}

// ------------------------------------------------------------------ launch
extern "C" void kernel_launch(void* const* d_in, const int* in_sizes, int n_in,
                              void* d_out, int out_size, void* d_ws, size_t ws_size,
                              hipStream_t stream) {
  const float* query = (const float*)d_in[0];
  const float* key   = (const float*)d_in[1];
  const float* value = (const float*)d_in[2];
  const float* Wq = (const float*)d_in[3];
  const float* bq = (const float*)d_in[4];
  const float* Wk = (const float*)d_in[5];
  const float* bk = (const float*)d_in[6];
  const float* Wv = (const float*)d_in[7];
  const float* bv = (const float*)d_in[8];
  const float* Wo = (const float*)d_in[9];
  const float* bo = (const float*)d_in[10];
  float* out = (float*)d_out;

  // workspace layout (u16 elements): total 28M u16 = 56 MB
  u16* WT = (u16*)d_ws;              // 4 x 1M  (Wq_t, Wk_t, Wv_t, Wo_t)
  u16* QN = WT + 4 * 1048576;        // 4M  natural [b,s,1024] (pre-scaled by CSC)
  u16* KN = QN + 4194304;            // 4M  natural [b,s,1024]
  u16* VT = KN + 4194304;            // 4M  [b,h,d,s]
  u16* XB = VT + 4194304;            // 3 x 4M bf16 copies of q,k,v
  u16* AO = XB;                      // attn out aliases XB (dead by then)

  convx<<<dim3(4096, 3), 256, 0, stream>>>(query, key, value, XB);
  transw<<<dim3(16, 16, 4), 256, 0, stream>>>(Wq, Wk, Wv, Wo, WT);
  qkv_gemm<<<dim3(256, 3), 256, 0, stream>>>(XB, WT, bq, bk, bv, QN, KN, VT);
  attn5<<<dim3(16, 16, 2), 512, 0, stream>>>(QN, KN, VT, AO);
  oproj_gemm<<<dim3(512), 256, 0, stream>>>(AO, WT + 3 * 1048576, bo, out);
}